// Round 3
// baseline (1220.956 us; speedup 1.0000x reference)
//
#include <hip/hip_runtime.h>
#include <hip/hip_bf16.h>
#include <stdint.h>

#define KDIM 1024
#define NROW 4096
#define NCOL 4096
#define INFV 1e30f
#define BM 128
#define BK 32

#define NWG   16                  // 16 WGs x 1 wave x 64 lanes x CPL cols = 4096
#define CPL   4                   // columns per lane
#define SS    4                   // rows per superstep
#define QD    6                   // cost prefetch depth in supersteps
#define NBLK  (NROW / SS)         // 1024 row-blocks
#define SSTOT 1092                // >= NBLK + 63, multiple of QD

typedef __bf16 bf16x8 __attribute__((ext_vector_type(8)));
typedef float f32x4 __attribute__((ext_vector_type(4)));

__device__ __forceinline__ unsigned short f2bf(float f) {
    __hip_bfloat16 h = __float2bfloat16(f);
    return *reinterpret_cast<unsigned short*>(&h);
}

// ---------------------------------------------------------------------------
// Kernel 1: row-normalize both trajectories, emit bf16
// ---------------------------------------------------------------------------
__global__ __launch_bounds__(256) void normalize_bf16(
    const float* __restrict__ t1, const float* __restrict__ t2,
    unsigned short* __restrict__ o1, unsigned short* __restrict__ o2)
{
    int b = blockIdx.x;
    int t = threadIdx.x;
    const float* src;
    unsigned short* dst;
    if (b < NROW) { src = t1 + (size_t)b * KDIM;          dst = o1 + (size_t)b * KDIM; }
    else          { src = t2 + (size_t)(b - NROW) * KDIM; dst = o2 + (size_t)(b - NROW) * KDIM; }

    float4 v = reinterpret_cast<const float4*>(src)[t];
    float ss = v.x * v.x + v.y * v.y + v.z * v.z + v.w * v.w;
    #pragma unroll
    for (int d = 32; d >= 1; d >>= 1) ss += __shfl_xor(ss, d, 64);

    __shared__ float wsum[4];
    int wave = t >> 6;
    if ((t & 63) == 0) wsum[wave] = ss;
    __syncthreads();
    float inv = 1.0f / (sqrtf(wsum[0] + wsum[1] + wsum[2] + wsum[3]) + 1e-8f);

    ushort4 o;
    o.x = f2bf(v.x * inv);
    o.y = f2bf(v.y * inv);
    o.z = f2bf(v.z * inv);
    o.w = f2bf(v.w * inv);
    reinterpret_cast<ushort4*>(dst)[t] = o;
}

// ---------------------------------------------------------------------------
// Kernel 2: cost[i][j] = 1 - dot(t1n[i], t2n[j])  (bf16 in, bf16 out)
// ---------------------------------------------------------------------------
__global__ __launch_bounds__(256) void gemm_cost(
    const unsigned short* __restrict__ A,
    const unsigned short* __restrict__ B,
    unsigned short* __restrict__ C)
{
    __shared__ __align__(16) unsigned short As[BM * BK];
    __shared__ __align__(16) unsigned short Bs[BM * BK];

    int t    = threadIdx.x;
    int lane = t & 63;
    int wave = t >> 6;
    int i0   = blockIdx.y * BM;
    int j0   = blockIdx.x * BM;

    f32x4 acc[4][4];
    f32x4 zero = {0.f, 0.f, 0.f, 0.f};
    #pragma unroll
    for (int m = 0; m < 4; ++m)
        #pragma unroll
        for (int n = 0; n < 4; ++n) acc[m][n] = zero;

    int frow = lane & 15;
    int fk   = (lane >> 4) * 8;
    int wr   = (wave >> 1) * 64;
    int wc   = (wave & 1) * 64;

    int srow = t >> 2;
    int scb  = (t & 3) * 8;

    uint4 ra0, ra1, rb0, rb1;
    {
        ra0 = *reinterpret_cast<const uint4*>(A + (size_t)(i0 + srow) * KDIM + scb);
        ra1 = *reinterpret_cast<const uint4*>(A + (size_t)(i0 + 64 + srow) * KDIM + scb);
        rb0 = *reinterpret_cast<const uint4*>(B + (size_t)(j0 + srow) * KDIM + scb);
        rb1 = *reinterpret_cast<const uint4*>(B + (size_t)(j0 + 64 + srow) * KDIM + scb);
    }

    for (int k0 = 0; k0 < KDIM; k0 += BK) {
        __syncthreads();
        *reinterpret_cast<uint4*>(As + (size_t)t * 8)         = ra0;
        *reinterpret_cast<uint4*>(As + (size_t)(256 + t) * 8) = ra1;
        *reinterpret_cast<uint4*>(Bs + (size_t)t * 8)         = rb0;
        *reinterpret_cast<uint4*>(Bs + (size_t)(256 + t) * 8) = rb1;
        __syncthreads();

        if (k0 + BK < KDIM) {
            int kn = k0 + BK;
            ra0 = *reinterpret_cast<const uint4*>(A + (size_t)(i0 + srow) * KDIM + kn + scb);
            ra1 = *reinterpret_cast<const uint4*>(A + (size_t)(i0 + 64 + srow) * KDIM + kn + scb);
            rb0 = *reinterpret_cast<const uint4*>(B + (size_t)(j0 + srow) * KDIM + kn + scb);
            rb1 = *reinterpret_cast<const uint4*>(B + (size_t)(j0 + 64 + srow) * KDIM + kn + scb);
        }

        bf16x8 af[4], bfr[4];
        #pragma unroll
        for (int m = 0; m < 4; ++m)
            af[m] = *reinterpret_cast<const bf16x8*>(As + (wr + m * 16 + frow) * BK + fk);
        #pragma unroll
        for (int n = 0; n < 4; ++n)
            bfr[n] = *reinterpret_cast<const bf16x8*>(Bs + (wc + n * 16 + frow) * BK + fk);

        #pragma unroll
        for (int m = 0; m < 4; ++m)
            #pragma unroll
            for (int n = 0; n < 4; ++n)
                acc[m][n] = __builtin_amdgcn_mfma_f32_16x16x32_bf16(af[m], bfr[n], acc[m][n], 0, 0, 0);
    }

    int crow = (lane >> 4) * 4;
    int ccol = lane & 15;
    #pragma unroll
    for (int m = 0; m < 4; ++m)
        #pragma unroll
        for (int n = 0; n < 4; ++n) {
            size_t base = (size_t)(i0 + wr + m * 16 + crow) * NCOL + (j0 + wc + n * 16 + ccol);
            #pragma unroll
            for (int q = 0; q < 4; ++q)
                C[base + (size_t)q * NCOL] = f2bf(1.0f - acc[m][n][q]);
        }
}

// ---------------------------------------------------------------------------
// Kernel 3: superstep systolic DTW.
// Lane L of WG w owns CPL=4 cols starting at (64w+L)*4. At superstep ss it
// computes SS=4 rows of block (ss - L) for its cols. Right boundary (d3 of
// each row) passes to lane+1 via shfl_up, consumed next superstep. WG
// boundary via (tag,value) 8B relaxed agent atomics, one slot per row,
// prefetched one superstep ahead.
// ---------------------------------------------------------------------------
__global__ __launch_bounds__(64, 1) void dtw_systolic(
    const unsigned short* __restrict__ cost,
    unsigned long long* __restrict__ ring,   // [NWG-1][NROW]
    float* __restrict__ out)
{
    const int w    = blockIdx.x;
    const int lane = threadIdx.x;
    const char* cb = (const char*)cost;
    const size_t colByte = (size_t)(w * 64 + lane) * (CPL * 2);

    // cost prefetch: cq[qi][k] holds row ((sb+qi) - lane)*SS + k (clamped)
    uint2 cq[QD][SS];
    #pragma unroll
    for (int qi = 0; qi < QD; ++qi)
        #pragma unroll
        for (int k = 0; k < SS; ++k) {
            int r = (qi - lane) * SS + k;
            r = r < 0 ? 0 : (r > NROW - 1 ? NROW - 1 : r);
            cq[qi][k] = *reinterpret_cast<const uint2*>(cb + ((size_t)r << 13) + colByte);
        }

    // boundary prefetch (lane 0, w>0): slots for block ss=0
    unsigned long long bq[SS];
    if (w > 0 && lane == 0) {
        #pragma unroll
        for (int k = 0; k < SS; ++k)
            bq[k] = __hip_atomic_load(ring + (size_t)(w - 1) * NROW + k,
                                      __ATOMIC_RELAXED, __HIP_MEMORY_SCOPE_AGENT);
    }

    float pd0 = INFV, pd1 = INFV, pd2 = INFV, pd3 = INFV;
    float lb[SS];
    #pragma unroll
    for (int k = 0; k < SS; ++k) lb[k] = INFV;
    float dseed = (w == 0 && lane == 0) ? 0.0f : INFV;
    float ans = 0.0f;

    for (int sb = 0; sb < SSTOT; sb += QD) {
        #pragma unroll
        for (int qi = 0; qi < QD; ++qi) {
            const int ss = sb + qi;

            // lane 0: resolve left boundary for this block
            if (lane == 0) {
                if (w == 0) {
                    #pragma unroll
                    for (int k = 0; k < SS; ++k) lb[k] = INFV;
                } else if (ss < NBLK) {
                    const unsigned long long* base = ring + (size_t)(w - 1) * NROW;
                    #pragma unroll
                    for (int k = 0; k < SS; ++k) {
                        const int r = ss * SS + k;
                        unsigned long long v = bq[k];
                        if ((unsigned)v != (unsigned)(r + 1)) {
                            do {
                                v = __hip_atomic_load(base + r, __ATOMIC_RELAXED,
                                                      __HIP_MEMORY_SCOPE_AGENT);
                            } while ((unsigned)v != (unsigned)(r + 1));
                        }
                        lb[k] = __uint_as_float((unsigned)(v >> 32));
                    }
                    if (ss + 1 < NBLK) {
                        #pragma unroll
                        for (int k = 0; k < SS; ++k)
                            bq[k] = __hip_atomic_load(base + (ss + 1) * SS + k,
                                                      __ATOMIC_RELAXED, __HIP_MEMORY_SCOPE_AGENT);
                    }
                }
            }

            // compute SS rows x CPL cols
            float nlb[SS];
            #pragma unroll
            for (int k = 0; k < SS; ++k) {
                const uint2 cu = cq[qi][k];
                const float c0 = __uint_as_float(cu.x << 16);
                const float c1 = __uint_as_float(cu.x & 0xffff0000u);
                const float c2 = __uint_as_float(cu.y << 16);
                const float c3 = __uint_as_float(cu.y & 0xffff0000u);
                const float diag = (k == 0) ? dseed : lb[k - 1];
                const float d0 = c0 + fminf(fminf(lb[k], pd0), diag);
                const float d1 = c1 + fminf(fminf(d0, pd1), pd0);
                const float d2 = c2 + fminf(fminf(d1, pd2), pd1);
                const float d3 = c3 + fminf(fminf(d2, pd3), pd2);
                pd0 = d0; pd1 = d1; pd2 = d2; pd3 = d3;
                nlb[k] = __shfl_up(d3, 1, 64);

                if (w < NWG - 1) {
                    const int blk = ss - 63;
                    if (lane == 63 && (unsigned)blk < (unsigned)NBLK) {
                        const int r = blk * SS + k;
                        const unsigned long long pk =
                            ((unsigned long long)__float_as_uint(d3) << 32) | (unsigned)(r + 1);
                        __hip_atomic_store(ring + (size_t)w * NROW + r, pk,
                                           __ATOMIC_RELAXED, __HIP_MEMORY_SCOPE_AGENT);
                    }
                } else if (lane == 63 && ss == NBLK - 1 + 63 && k == SS - 1) {
                    ans = d3;
                }
            }

            dseed = lb[SS - 1];
            #pragma unroll
            for (int k = 0; k < SS; ++k) lb[k] = nlb[k];

            // reissue cost prefetch for superstep ss+QD
            #pragma unroll
            for (int k = 0; k < SS; ++k) {
                int r = (ss + QD - lane) * SS + k;
                r = r < 0 ? 0 : (r > NROW - 1 ? NROW - 1 : r);
                cq[qi][k] = *reinterpret_cast<const uint2*>(cb + ((size_t)r << 13) + colByte);
            }
        }
    }

    if (w == NWG - 1 && lane == 63) out[0] = 1.0f / (1.0f + ans);
}

// ---------------------------------------------------------------------------
extern "C" void kernel_launch(void* const* d_in, const int* in_sizes, int n_in,
                              void* d_out, int out_size, void* d_ws, size_t ws_size,
                              hipStream_t stream)
{
    const float* t1 = (const float*)d_in[0];
    const float* t2 = (const float*)d_in[1];
    float* out = (float*)d_out;

    char* ws = (char*)d_ws;
    unsigned short* t1n  = (unsigned short*)ws;                                   // 8 MB
    unsigned short* t2n  = (unsigned short*)(ws + (size_t)NROW * KDIM * 2);       // 8 MB
    unsigned short* cost = (unsigned short*)(ws + (size_t)2 * NROW * KDIM * 2);   // 32 MB
    unsigned long long* ring = (unsigned long long*)(ws + (size_t)48 * 1024 * 1024); // 480 KB

    hipMemsetAsync(ring, 0, (size_t)(NWG - 1) * NROW * 8, stream);
    normalize_bf16<<<2 * NROW, 256, 0, stream>>>(t1, t2, t1n, t2n);
    gemm_cost<<<dim3(NCOL / BM, NROW / BM), 256, 0, stream>>>(t1n, t2n, cost);
    dtw_systolic<<<NWG, 64, 0, stream>>>(cost, ring, out);
}

// Round 4
// 858.779 us; speedup vs baseline: 1.4217x; 1.4217x over previous
//
#include <hip/hip_runtime.h>
#include <hip/hip_bf16.h>
#include <stdint.h>

#define KDIM 1024
#define NROW 4096
#define NCOL 4096
#define INFV 1e30f
#define INFBITS 0x7149F2CAu     // bits of 1e30f
#define BM 128
#define BK 32

#define NWG    16               // 16 WGs x 1 wave x 64 lanes x 4 cols = 4096 columns
#define UNR    8                // modulo-scheduled prefetch depth (steps)
#define SSTEPS 4160             // NROW + 64, multiple of UNR

typedef __bf16 bf16x8 __attribute__((ext_vector_type(8)));
typedef float f32x4 __attribute__((ext_vector_type(4)));

__device__ __forceinline__ unsigned short f2bf(float f) {
    __hip_bfloat16 h = __float2bfloat16(f);
    return *reinterpret_cast<unsigned short*>(&h);
}

// ---------------------------------------------------------------------------
// Kernel 1: row-normalize both trajectories, emit bf16
// ---------------------------------------------------------------------------
__global__ __launch_bounds__(256) void normalize_bf16(
    const float* __restrict__ t1, const float* __restrict__ t2,
    unsigned short* __restrict__ o1, unsigned short* __restrict__ o2)
{
    int b = blockIdx.x;
    int t = threadIdx.x;
    const float* src;
    unsigned short* dst;
    if (b < NROW) { src = t1 + (size_t)b * KDIM;          dst = o1 + (size_t)b * KDIM; }
    else          { src = t2 + (size_t)(b - NROW) * KDIM; dst = o2 + (size_t)(b - NROW) * KDIM; }

    float4 v = reinterpret_cast<const float4*>(src)[t];
    float ss = v.x * v.x + v.y * v.y + v.z * v.z + v.w * v.w;
    #pragma unroll
    for (int d = 32; d >= 1; d >>= 1) ss += __shfl_xor(ss, d, 64);

    __shared__ float wsum[4];
    int wave = t >> 6;
    if ((t & 63) == 0) wsum[wave] = ss;
    __syncthreads();
    float inv = 1.0f / (sqrtf(wsum[0] + wsum[1] + wsum[2] + wsum[3]) + 1e-8f);

    ushort4 o;
    o.x = f2bf(v.x * inv);
    o.y = f2bf(v.y * inv);
    o.z = f2bf(v.z * inv);
    o.w = f2bf(v.w * inv);
    reinterpret_cast<ushort4*>(dst)[t] = o;
}

// ---------------------------------------------------------------------------
// Kernel 2: cost[i][j] = 1 - dot(t1n[i], t2n[j])  (bf16 in, bf16 out)
// ---------------------------------------------------------------------------
__global__ __launch_bounds__(256) void gemm_cost(
    const unsigned short* __restrict__ A,
    const unsigned short* __restrict__ B,
    unsigned short* __restrict__ C)
{
    __shared__ __align__(16) unsigned short As[BM * BK];
    __shared__ __align__(16) unsigned short Bs[BM * BK];

    int t    = threadIdx.x;
    int lane = t & 63;
    int wave = t >> 6;
    int i0   = blockIdx.y * BM;
    int j0   = blockIdx.x * BM;

    f32x4 acc[4][4];
    f32x4 zero = {0.f, 0.f, 0.f, 0.f};
    #pragma unroll
    for (int m = 0; m < 4; ++m)
        #pragma unroll
        for (int n = 0; n < 4; ++n) acc[m][n] = zero;

    int frow = lane & 15;
    int fk   = (lane >> 4) * 8;
    int wr   = (wave >> 1) * 64;
    int wc   = (wave & 1) * 64;

    int srow = t >> 2;
    int scb  = (t & 3) * 8;

    uint4 ra0, ra1, rb0, rb1;
    {
        ra0 = *reinterpret_cast<const uint4*>(A + (size_t)(i0 + srow) * KDIM + scb);
        ra1 = *reinterpret_cast<const uint4*>(A + (size_t)(i0 + 64 + srow) * KDIM + scb);
        rb0 = *reinterpret_cast<const uint4*>(B + (size_t)(j0 + srow) * KDIM + scb);
        rb1 = *reinterpret_cast<const uint4*>(B + (size_t)(j0 + 64 + srow) * KDIM + scb);
    }

    for (int k0 = 0; k0 < KDIM; k0 += BK) {
        __syncthreads();
        *reinterpret_cast<uint4*>(As + (size_t)t * 8)         = ra0;
        *reinterpret_cast<uint4*>(As + (size_t)(256 + t) * 8) = ra1;
        *reinterpret_cast<uint4*>(Bs + (size_t)t * 8)         = rb0;
        *reinterpret_cast<uint4*>(Bs + (size_t)(256 + t) * 8) = rb1;
        __syncthreads();

        if (k0 + BK < KDIM) {
            int kn = k0 + BK;
            ra0 = *reinterpret_cast<const uint4*>(A + (size_t)(i0 + srow) * KDIM + kn + scb);
            ra1 = *reinterpret_cast<const uint4*>(A + (size_t)(i0 + 64 + srow) * KDIM + kn + scb);
            rb0 = *reinterpret_cast<const uint4*>(B + (size_t)(j0 + srow) * KDIM + kn + scb);
            rb1 = *reinterpret_cast<const uint4*>(B + (size_t)(j0 + 64 + srow) * KDIM + kn + scb);
        }

        bf16x8 af[4], bfr[4];
        #pragma unroll
        for (int m = 0; m < 4; ++m)
            af[m] = *reinterpret_cast<const bf16x8*>(As + (wr + m * 16 + frow) * BK + fk);
        #pragma unroll
        for (int n = 0; n < 4; ++n)
            bfr[n] = *reinterpret_cast<const bf16x8*>(Bs + (wc + n * 16 + frow) * BK + fk);

        #pragma unroll
        for (int m = 0; m < 4; ++m)
            #pragma unroll
            for (int n = 0; n < 4; ++n)
                acc[m][n] = __builtin_amdgcn_mfma_f32_16x16x32_bf16(af[m], bfr[n], acc[m][n], 0, 0, 0);
    }

    int crow = (lane >> 4) * 4;
    int ccol = lane & 15;
    #pragma unroll
    for (int m = 0; m < 4; ++m)
        #pragma unroll
        for (int n = 0; n < 4; ++n) {
            size_t base = (size_t)(i0 + wr + m * 16 + crow) * NCOL + (j0 + wc + n * 16 + ccol);
            #pragma unroll
            for (int q = 0; q < 4; ++q)
                C[base + (size_t)q * NCOL] = f2bf(1.0f - acc[m][n][q]);
        }
}

// ---------------------------------------------------------------------------
// ring_init: prefill the dummy segment (index NWG-1) read by WG 0:
// tag = row+1 (always valid), value = +INF. Lets all WGs run identical code.
// ---------------------------------------------------------------------------
__global__ __launch_bounds__(256) void ring_init(unsigned long long* __restrict__ ring)
{
    int i = blockIdx.x * 256 + threadIdx.x;
    ring[(size_t)(NWG - 1) * NROW + i] =
        ((unsigned long long)INFBITS << 32) | (unsigned)(i + 1);
}

// ---------------------------------------------------------------------------
// Kernel 3: systolic DTW, DPP wave_shr:1 lane handoff, named-register
// modulo-scheduled prefetch (depth UNR=8) for cost rows and ring slots.
// Lane L of WG w owns cols [4*(64w+L), +4); at step t it computes row t-L.
// lcur = D[row][left] arrives via DPP from lane-1 (lane 0: from ring value,
// injected through the DPP 'old' operand). Recurrence per 4-col cell block:
//   e0 = c0 + min3(lcur, pd0, lprev)   (left, up, diag)
//   ek = ck + min3(e{k-1}, pdk, pd{k-1})
// ---------------------------------------------------------------------------
__global__ __launch_bounds__(64, 1) void dtw_systolic(
    const unsigned short* __restrict__ cost,
    unsigned long long* __restrict__ ring,   // [NWG][NROW]; seg NWG-1 = dummy
    float* __restrict__ out)
{
    const int w    = blockIdx.x;
    const int lane = threadIdx.x;
    const char* cb = (const char*)cost;
    const int colByte = (w * 64 + lane) * 8;          // 4 bf16 = 8 B per lane
    const unsigned long long* rseg =
        ring + (size_t)((w == 0) ? (NWG - 1) : (w - 1)) * NROW;
    unsigned long long* wseg = ring + (size_t)w * NROW;
    const bool last = (w == NWG - 1);

    float pd0 = INFV, pd1 = INFV, pd2 = INFV, pd3 = INFV;
    float lprev = (w == 0 && lane == 0) ? 0.0f : INFV;  // diag seed (DP origin)
    float d3p = INFV;                                   // own d3 of previous row
    float ans = INFV;

    uint2 q0, q1, q2, q3, q4, q5, q6, q7;
    unsigned long long rv0, rv1, rv2, rv3, rv4, rv5, rv6, rv7;

#define PRO(J) { \
        int r = J - lane; r = r < 0 ? 0 : r; \
        q##J = *reinterpret_cast<const uint2*>(cb + ((size_t)r << 13) + colByte); \
        rv##J = __hip_atomic_load(rseg + J, __ATOMIC_RELAXED, __HIP_MEMORY_SCOPE_AGENT); }
    PRO(0) PRO(1) PRO(2) PRO(3) PRO(4) PRO(5) PRO(6) PRO(7)
#undef PRO

#define STEP(J) { \
        const int tj = t + J; \
        const int slot = (tj < NROW - 1) ? tj : (NROW - 1); \
        const unsigned expt = (unsigned)(slot + 1); \
        unsigned long long v = rv##J; \
        if ((unsigned)v != expt) { \
            do { v = __hip_atomic_load(rseg + slot, __ATOMIC_RELAXED, \
                                       __HIP_MEMORY_SCOPE_AGENT); } \
            while ((unsigned)v != expt); \
        } \
        const int rvb = (int)(unsigned)(v >> 32); \
        const float lcur = __uint_as_float((unsigned)__builtin_amdgcn_update_dpp( \
            rvb, (int)__float_as_uint(d3p), 0x138, 0xf, 0xf, false)); \
        const uint2 cu = q##J; \
        const float c0 = __uint_as_float(cu.x << 16); \
        const float c1 = __uint_as_float(cu.x & 0xffff0000u); \
        const float c2 = __uint_as_float(cu.y << 16); \
        const float c3 = __uint_as_float(cu.y & 0xffff0000u); \
        const float e0 = c0 + fminf(fminf(lcur, pd0), lprev); \
        const float e1 = c1 + fminf(fminf(e0, pd1), pd0); \
        const float e2 = c2 + fminf(fminf(e1, pd2), pd1); \
        const float e3 = c3 + fminf(fminf(e2, pd3), pd2); \
        if (!last) { \
            const int rp = tj - 63; \
            if (lane == 63 && (unsigned)rp < (unsigned)NROW) { \
                const unsigned long long pk = \
                    ((unsigned long long)__float_as_uint(e3) << 32) | (unsigned)(rp + 1); \
                __hip_atomic_store(wseg + rp, pk, __ATOMIC_RELAXED, \
                                   __HIP_MEMORY_SCOPE_AGENT); \
            } \
        } else if (tj == NROW - 1 + 63) { \
            ans = e3; \
        } \
        lprev = lcur; d3p = e3; \
        pd0 = e0; pd1 = e1; pd2 = e2; pd3 = e3; \
        { \
            const int nr = tj + UNR; \
            int rq = nr - lane; \
            rq = rq < 0 ? 0 : (rq > NROW - 1 ? NROW - 1 : rq); \
            q##J = *reinterpret_cast<const uint2*>(cb + ((size_t)rq << 13) + colByte); \
            const int rs = (nr < NROW - 1) ? nr : (NROW - 1); \
            rv##J = __hip_atomic_load(rseg + rs, __ATOMIC_RELAXED, \
                                      __HIP_MEMORY_SCOPE_AGENT); \
        } }

    for (int t = 0; t < SSTEPS; t += UNR) {
        STEP(0) STEP(1) STEP(2) STEP(3) STEP(4) STEP(5) STEP(6) STEP(7)
    }
#undef STEP

    if (last && lane == 63) out[0] = 1.0f / (1.0f + ans);
}

// ---------------------------------------------------------------------------
extern "C" void kernel_launch(void* const* d_in, const int* in_sizes, int n_in,
                              void* d_out, int out_size, void* d_ws, size_t ws_size,
                              hipStream_t stream)
{
    const float* t1 = (const float*)d_in[0];
    const float* t2 = (const float*)d_in[1];
    float* out = (float*)d_out;

    char* ws = (char*)d_ws;
    unsigned short* t1n  = (unsigned short*)ws;                                   // 8 MB
    unsigned short* t2n  = (unsigned short*)(ws + (size_t)NROW * KDIM * 2);       // 8 MB
    unsigned short* cost = (unsigned short*)(ws + (size_t)2 * NROW * KDIM * 2);   // 32 MB
    unsigned long long* ring = (unsigned long long*)(ws + (size_t)48 * 1024 * 1024); // 512 KB

    // clear real segments 0..NWG-2, prefill dummy segment NWG-1
    hipMemsetAsync(ring, 0, (size_t)(NWG - 1) * NROW * 8, stream);
    ring_init<<<NROW / 256, 256, 0, stream>>>(ring);
    normalize_bf16<<<2 * NROW, 256, 0, stream>>>(t1, t2, t1n, t2n);
    gemm_cost<<<dim3(NCOL / BM, NROW / BM), 256, 0, stream>>>(t1n, t2n, cost);
    dtw_systolic<<<NWG, 64, 0, stream>>>(cost, ring, out);
}

// Round 5
// 829.982 us; speedup vs baseline: 1.4711x; 1.0347x over previous
//
#include <hip/hip_runtime.h>
#include <hip/hip_bf16.h>
#include <stdint.h>

#define KDIM 1024
#define NROW 4096
#define NCOL 4096
#define INFV 1e30f
#define INFBITS 0x7149F2CAu     // bits of 1e30f
#define BM 128
#define BK 32

#define NWG    16               // 16 WGs x 1 wave x 64 lanes x 4 cols = 4096 columns
#define UNR    16               // modulo-scheduled prefetch depth (steps)
#define SSTEPS 4160             // NROW + 64, multiple of UNR
#define SKROWS 4160             // skewed cost rows

typedef __bf16 bf16x8 __attribute__((ext_vector_type(8)));
typedef float f32x4 __attribute__((ext_vector_type(4)));

__device__ __forceinline__ unsigned short f2bf(float f) {
    __hip_bfloat16 h = __float2bfloat16(f);
    return *reinterpret_cast<unsigned short*>(&h);
}

// ---------------------------------------------------------------------------
// Kernel 1: row-normalize both trajectories, emit bf16
// ---------------------------------------------------------------------------
__global__ __launch_bounds__(256) void normalize_bf16(
    const float* __restrict__ t1, const float* __restrict__ t2,
    unsigned short* __restrict__ o1, unsigned short* __restrict__ o2)
{
    int b = blockIdx.x;
    int t = threadIdx.x;
    const float* src;
    unsigned short* dst;
    if (b < NROW) { src = t1 + (size_t)b * KDIM;          dst = o1 + (size_t)b * KDIM; }
    else          { src = t2 + (size_t)(b - NROW) * KDIM; dst = o2 + (size_t)(b - NROW) * KDIM; }

    float4 v = reinterpret_cast<const float4*>(src)[t];
    float ss = v.x * v.x + v.y * v.y + v.z * v.z + v.w * v.w;
    #pragma unroll
    for (int d = 32; d >= 1; d >>= 1) ss += __shfl_xor(ss, d, 64);

    __shared__ float wsum[4];
    int wave = t >> 6;
    if ((t & 63) == 0) wsum[wave] = ss;
    __syncthreads();
    float inv = 1.0f / (sqrtf(wsum[0] + wsum[1] + wsum[2] + wsum[3]) + 1e-8f);

    ushort4 o;
    o.x = f2bf(v.x * inv);
    o.y = f2bf(v.y * inv);
    o.z = f2bf(v.z * inv);
    o.w = f2bf(v.w * inv);
    reinterpret_cast<ushort4*>(dst)[t] = o;
}

// ---------------------------------------------------------------------------
// Kernel 2: skewed cost: skew[i + ((j>>2)&63)][j] = 1 - dot(t1n[i], t2n[j])
// so the systolic kernel's per-step wave read (lane L <- row t-L) is one
// coalesced 512B load from skew row t.
// ---------------------------------------------------------------------------
__global__ __launch_bounds__(256) void gemm_cost(
    const unsigned short* __restrict__ A,
    const unsigned short* __restrict__ B,
    unsigned short* __restrict__ Cs)    // skewed [SKROWS][4096]
{
    __shared__ __align__(16) unsigned short As[BM * BK];
    __shared__ __align__(16) unsigned short Bs[BM * BK];

    int t    = threadIdx.x;
    int lane = t & 63;
    int wave = t >> 6;
    int i0   = blockIdx.y * BM;
    int j0   = blockIdx.x * BM;

    f32x4 acc[4][4];
    f32x4 zero = {0.f, 0.f, 0.f, 0.f};
    #pragma unroll
    for (int m = 0; m < 4; ++m)
        #pragma unroll
        for (int n = 0; n < 4; ++n) acc[m][n] = zero;

    int frow = lane & 15;
    int fk   = (lane >> 4) * 8;
    int wr   = (wave >> 1) * 64;
    int wc   = (wave & 1) * 64;

    int srow = t >> 2;
    int scb  = (t & 3) * 8;

    uint4 ra0, ra1, rb0, rb1;
    {
        ra0 = *reinterpret_cast<const uint4*>(A + (size_t)(i0 + srow) * KDIM + scb);
        ra1 = *reinterpret_cast<const uint4*>(A + (size_t)(i0 + 64 + srow) * KDIM + scb);
        rb0 = *reinterpret_cast<const uint4*>(B + (size_t)(j0 + srow) * KDIM + scb);
        rb1 = *reinterpret_cast<const uint4*>(B + (size_t)(j0 + 64 + srow) * KDIM + scb);
    }

    for (int k0 = 0; k0 < KDIM; k0 += BK) {
        __syncthreads();
        *reinterpret_cast<uint4*>(As + (size_t)t * 8)         = ra0;
        *reinterpret_cast<uint4*>(As + (size_t)(256 + t) * 8) = ra1;
        *reinterpret_cast<uint4*>(Bs + (size_t)t * 8)         = rb0;
        *reinterpret_cast<uint4*>(Bs + (size_t)(256 + t) * 8) = rb1;
        __syncthreads();

        if (k0 + BK < KDIM) {
            int kn = k0 + BK;
            ra0 = *reinterpret_cast<const uint4*>(A + (size_t)(i0 + srow) * KDIM + kn + scb);
            ra1 = *reinterpret_cast<const uint4*>(A + (size_t)(i0 + 64 + srow) * KDIM + kn + scb);
            rb0 = *reinterpret_cast<const uint4*>(B + (size_t)(j0 + srow) * KDIM + kn + scb);
            rb1 = *reinterpret_cast<const uint4*>(B + (size_t)(j0 + 64 + srow) * KDIM + kn + scb);
        }

        bf16x8 af[4], bfr[4];
        #pragma unroll
        for (int m = 0; m < 4; ++m)
            af[m] = *reinterpret_cast<const bf16x8*>(As + (wr + m * 16 + frow) * BK + fk);
        #pragma unroll
        for (int n = 0; n < 4; ++n)
            bfr[n] = *reinterpret_cast<const bf16x8*>(Bs + (wc + n * 16 + frow) * BK + fk);

        #pragma unroll
        for (int m = 0; m < 4; ++m)
            #pragma unroll
            for (int n = 0; n < 4; ++n)
                acc[m][n] = __builtin_amdgcn_mfma_f32_16x16x32_bf16(af[m], bfr[n], acc[m][n], 0, 0, 0);
    }

    int crow = (lane >> 4) * 4;
    int ccol = lane & 15;
    #pragma unroll
    for (int n = 0; n < 4; ++n) {
        const int j  = j0 + wc + n * 16 + ccol;
        const int Lj = (j >> 2) & 63;
        #pragma unroll
        for (int m = 0; m < 4; ++m) {
            const int ibase = i0 + wr + m * 16 + crow;
            #pragma unroll
            for (int q = 0; q < 4; ++q)
                Cs[(size_t)(ibase + q + Lj) * NCOL + j] = f2bf(1.0f - acc[m][n][q]);
        }
    }
}

// ---------------------------------------------------------------------------
// ring_init: prefill the dummy segment (index NWG-1) read by WG 0:
// tag = row+1 (always valid), value = +INF.
// ---------------------------------------------------------------------------
__global__ __launch_bounds__(256) void ring_init(unsigned long long* __restrict__ ring)
{
    int i = blockIdx.x * 256 + threadIdx.x;
    ring[(size_t)(NWG - 1) * NROW + i] =
        ((unsigned long long)INFBITS << 32) | (unsigned)(i + 1);
}

// ---------------------------------------------------------------------------
// Kernel 3: systolic DTW on the skewed cost buffer.
// Named-register modulo pipeline (UNR=16); per-step asm memory fence pins
// each prefetch load to its issue step (stops the compiler sinking loads to
// their use 16 steps later). DPP wave_shr:1 hands d3 to lane+1; the DPP
// 'old' operand injects the ring boundary value into lane 0.
// ---------------------------------------------------------------------------
__global__ __launch_bounds__(64, 1) void dtw_systolic(
    const unsigned short* __restrict__ cost,   // skewed [SKROWS][4096]
    unsigned long long* __restrict__ ring,     // [NWG][NROW]; seg NWG-1 = dummy
    float* __restrict__ out)
{
    const int w    = blockIdx.x;
    const int lane = threadIdx.x;
    const char* cb = (const char*)cost;
    const unsigned colByte = (unsigned)(w * 64 + lane) * 8u;   // 4 bf16 = 8 B
    const unsigned loA = ((unsigned)lane << 13) + colByte;             // t = lane  (row 0)
    const unsigned hiA = ((unsigned)(4095 + lane) << 13) + colByte;    // row 4095
    const unsigned long long* rseg =
        ring + (size_t)((w == 0) ? (NWG - 1) : (w - 1)) * NROW;
    unsigned long long* wseg = ring + (size_t)w * NROW;
    const bool last = (w == NWG - 1);

    float pd0 = INFV, pd1 = INFV, pd2 = INFV, pd3 = INFV;
    float lprev = (w == 0 && lane == 0) ? 0.0f : INFV;  // diag seed (DP origin)
    float d3p = INFV;                                   // own d3 of previous row
    float ans = INFV;

    uint2 q0, q1, q2, q3, q4, q5, q6, q7, q8, q9, q10, q11, q12, q13, q14, q15;
    unsigned long long rv0, rv1, rv2, rv3, rv4, rv5, rv6, rv7,
                       rv8, rv9, rv10, rv11, rv12, rv13, rv14, rv15;

#define PRO(J) { \
        unsigned a = ((unsigned)(J) << 13) + colByte; \
        a = a < loA ? loA : a; \
        q##J = *reinterpret_cast<const uint2*>(cb + a); \
        rv##J = __hip_atomic_load(rseg + (J), __ATOMIC_RELAXED, __HIP_MEMORY_SCOPE_AGENT); }
    PRO(0) PRO(1) PRO(2) PRO(3) PRO(4) PRO(5) PRO(6) PRO(7)
    PRO(8) PRO(9) PRO(10) PRO(11) PRO(12) PRO(13) PRO(14) PRO(15)
#undef PRO
    asm volatile("" ::: "memory");

#define STEP(J) { \
        const int tj = t + (J); \
        const int slot = (tj < NROW - 1) ? tj : (NROW - 1); \
        const unsigned expt = (unsigned)(slot + 1); \
        unsigned long long v = rv##J; \
        if ((unsigned)v != expt) { \
            do { v = __hip_atomic_load(rseg + slot, __ATOMIC_RELAXED, \
                                       __HIP_MEMORY_SCOPE_AGENT); } \
            while ((unsigned)v != expt); \
        } \
        const int rvb = (int)(unsigned)(v >> 32); \
        const float lcur = __uint_as_float((unsigned)__builtin_amdgcn_update_dpp( \
            rvb, (int)__float_as_uint(d3p), 0x138, 0xf, 0xf, false)); \
        const uint2 cu = q##J; \
        const float c0 = __uint_as_float(cu.x << 16); \
        const float c1 = __uint_as_float(cu.x & 0xffff0000u); \
        const float c2 = __uint_as_float(cu.y << 16); \
        const float c3 = __uint_as_float(cu.y & 0xffff0000u); \
        const float e0 = c0 + fminf(fminf(lcur, pd0), lprev); \
        const float e1 = c1 + fminf(fminf(e0, pd1), pd0); \
        const float e2 = c2 + fminf(fminf(e1, pd2), pd1); \
        const float e3 = c3 + fminf(fminf(e2, pd3), pd2); \
        if (!last) { \
            const int rp = tj - 63; \
            if (lane == 63 && (unsigned)rp < (unsigned)NROW) { \
                const unsigned long long pk = \
                    ((unsigned long long)__float_as_uint(e3) << 32) | (unsigned)(rp + 1); \
                __hip_atomic_store(wseg + rp, pk, __ATOMIC_RELAXED, \
                                   __HIP_MEMORY_SCOPE_AGENT); \
            } \
        } else if (tj == NROW - 1 + 63) { \
            ans = e3; \
        } \
        lprev = lcur; d3p = e3; \
        pd0 = e0; pd1 = e1; pd2 = e2; pd3 = e3; \
        { \
            const int nr = tj + UNR; \
            unsigned a = ((unsigned)nr << 13) + colByte; \
            a = a < loA ? loA : (a > hiA ? hiA : a); \
            q##J = *reinterpret_cast<const uint2*>(cb + a); \
            const int rs = (nr < NROW - 1) ? nr : (NROW - 1); \
            rv##J = __hip_atomic_load(rseg + rs, __ATOMIC_RELAXED, \
                                      __HIP_MEMORY_SCOPE_AGENT); \
        } \
        asm volatile("" ::: "memory"); }

    for (int t = 0; t < SSTEPS; t += UNR) {
        STEP(0) STEP(1) STEP(2) STEP(3) STEP(4) STEP(5) STEP(6) STEP(7)
        STEP(8) STEP(9) STEP(10) STEP(11) STEP(12) STEP(13) STEP(14) STEP(15)
    }
#undef STEP

    if (last && lane == 63) out[0] = 1.0f / (1.0f + ans);
}

// ---------------------------------------------------------------------------
extern "C" void kernel_launch(void* const* d_in, const int* in_sizes, int n_in,
                              void* d_out, int out_size, void* d_ws, size_t ws_size,
                              hipStream_t stream)
{
    const float* t1 = (const float*)d_in[0];
    const float* t2 = (const float*)d_in[1];
    float* out = (float*)d_out;

    char* ws = (char*)d_ws;
    unsigned short* t1n  = (unsigned short*)ws;                                   // 8 MB
    unsigned short* t2n  = (unsigned short*)(ws + (size_t)NROW * KDIM * 2);       // 8 MB
    unsigned short* skew = (unsigned short*)(ws + (size_t)16 * 1024 * 1024);      // 34.1 MB
    unsigned long long* ring = (unsigned long long*)(ws + (size_t)52 * 1024 * 1024); // 512 KB

    // clear real segments 0..NWG-2, prefill dummy segment NWG-1
    hipMemsetAsync(ring, 0, (size_t)(NWG - 1) * NROW * 8, stream);
    ring_init<<<NROW / 256, 256, 0, stream>>>(ring);
    normalize_bf16<<<2 * NROW, 256, 0, stream>>>(t1, t2, t1n, t2n);
    gemm_cost<<<dim3(NCOL / BM, NROW / BM), 256, 0, stream>>>(t1n, t2n, skew);
    dtw_systolic<<<NWG, 64, 0, stream>>>(skew, ring, out);
}